// Round 19
// baseline (146.737 us; speedup 1.0000x reference)
//
#include <hip/hip_runtime.h>

#define B_ 8
#define L_ 4096
#define D_ 512
#define M_ 64

typedef __attribute__((ext_vector_type(8))) short bh8;
typedef __attribute__((ext_vector_type(4))) float f4;
typedef __attribute__((ext_vector_type(4))) unsigned u32x4;

__device__ inline unsigned short f2bf(float f) {
  unsigned u = __float_as_uint(f);
  return (unsigned short)((u + 0x7fffu + ((u >> 16) & 1u)) >> 16);
}
__device__ inline unsigned packbf(float lo, float hi) {
  return (unsigned)f2bf(lo) | ((unsigned)f2bf(hi) << 16);
}

// ---------------- forward-DFT coefficient matrix (bf16), PLAIN row-major [r][l]
__global__ void k_ftab(unsigned short* __restrict__ F) {
  int t = blockIdx.x * 256 + threadIdx.x;  // 128*4096
  int r = t >> 12, l = t & 4095;
  int k = r & 63, part = r >> 6;
  int ph = (k * l) & (L_ - 1);
  double ang = 6.283185307179586476925286766559 * (double)ph / (double)L_;
  float v = part ? (float)(-sin(ang)) : (float)(cos(ang));
  F[t] = f2bf(v);
}

// ----------------------------------------- inverse-DFT coefficient matrix (bf16)
__global__ void k_gtab(unsigned short* __restrict__ G) {
  int t = blockIdx.x * 256 + threadIdx.x;  // L_*128
  int l = t >> 7, j = t & 127;
  int k = j & 63, part = j >> 6;
  int ph = (k * l) & (L_ - 1);
  double ang = 6.283185307179586476925286766559 * (double)ph / (double)L_;
  double ck = (k == 0 ? 1.0 : 2.0) / (double)L_;
  float v = part ? (float)(-ck * sin(ang)) : (float)(ck * cos(ang));
  G[t] = f2bf(v);
}

// ------------------------- stage 1: Qft = F(128x4096) * q[b](4096x512) via MFMA
__global__ __launch_bounds__(512, 4) void k_dft_mfma(
    const float* __restrict__ q, const unsigned short* __restrict__ F,
    float* __restrict__ pQ) {
  int tid = threadIdx.x;
  int dt = blockIdx.x, b = blockIdx.y, kc = blockIdx.z;
  int d0 = dt * 64;
  int lbase = kc * 512;

  int w = tid >> 6, lane = tid & 63;
  int mh = w & 3, nc = w >> 2;
  int lr = lane & 15, kg = lane >> 4;

  f4 acc[2][2];
#pragma unroll
  for (int i = 0; i < 2; ++i)
#pragma unroll
    for (int j = 0; j < 2; ++j) { f4 z = {0.f, 0.f, 0.f, 0.f}; acc[i][j] = z; }

  const unsigned short* A0 = F + (size_t)(mh * 32 + lr) * 4096 + lbase + kg * 8;
  const unsigned short* A1 = A0 + (size_t)16 * 4096;
  const float* q0 = q + ((size_t)b * L_ + lbase + kg * 8) * D_ + d0 + nc * 32 + lr;

#pragma unroll 2
  for (int s = 0; s < 16; ++s) {
    const float* qs = q0 + (size_t)s * 32 * D_;
    float v0[8], v1[8];
#pragma unroll
    for (int j = 0; j < 8; ++j) {
      v0[j] = qs[(size_t)j * D_];
      v1[j] = qs[(size_t)j * D_ + 16];
    }
    union { u32x4 u; bh8 h; } bf0, bf1;
    bf0.u.x = packbf(v0[0], v0[1]); bf0.u.y = packbf(v0[2], v0[3]);
    bf0.u.z = packbf(v0[4], v0[5]); bf0.u.w = packbf(v0[6], v0[7]);
    bf1.u.x = packbf(v1[0], v1[1]); bf1.u.y = packbf(v1[2], v1[3]);
    bf1.u.z = packbf(v1[4], v1[5]); bf1.u.w = packbf(v1[6], v1[7]);
    bh8 af0 = *(const bh8*)(A0 + s * 32);
    bh8 af1 = *(const bh8*)(A1 + s * 32);
    acc[0][0] = __builtin_amdgcn_mfma_f32_16x16x32_bf16(af0, bf0.h, acc[0][0], 0, 0, 0);
    acc[0][1] = __builtin_amdgcn_mfma_f32_16x16x32_bf16(af0, bf1.h, acc[0][1], 0, 0, 0);
    acc[1][0] = __builtin_amdgcn_mfma_f32_16x16x32_bf16(af1, bf0.h, acc[1][0], 0, 0, 0);
    acc[1][1] = __builtin_amdgcn_mfma_f32_16x16x32_bf16(af1, bf1.h, acc[1][1], 0, 0, 0);
  }

#pragma unroll
  for (int mi = 0; mi < 2; ++mi) {
    int r = mh * 32 + mi * 16 + kg * 4;
#pragma unroll
    for (int ni = 0; ni < 2; ++ni) {
      int d = d0 + nc * 32 + ni * 16 + lr;
#pragma unroll
      for (int j = 0; j < 4; ++j)
        pQ[(((size_t)kc * 128 + (r + j)) * 8 + b) * 512 + d] = acc[mi][ni][j];
    }
  }
}

// -------------- reduce kc chunks + pack bf16 Qbf[k][b][d]: word = (Qr, Qi)
__global__ __launch_bounds__(256) void k_red2(const float* __restrict__ pQ,
                                              unsigned* __restrict__ Qbf) {
  int g = blockIdx.x * 256 + threadIdx.x;  // 64*8*128 = 65536
  int dq = g & 127;
  int b = (g >> 7) & 7;
  int k = g >> 10;
  f4 sr = {0.f, 0.f, 0.f, 0.f}, si = {0.f, 0.f, 0.f, 0.f};
#pragma unroll
  for (int kc = 0; kc < 8; ++kc) {
    size_t base = (((size_t)kc * 128 + k) * 8 + b) * 512 + dq * 4;
    sr += *(const f4*)(pQ + base);
    si += *(const f4*)(pQ + base + (size_t)64 * 8 * 512);
  }
  u32x4 o;
  o.x = packbf(sr[0], si[0]); o.y = packbf(sr[1], si[1]);
  o.z = packbf(sr[2], si[2]); o.w = packbf(sr[3], si[3]);
  *(u32x4*)(Qbf + ((size_t)k * 8 + b) * 512 + dq * 4) = o;
}

// ------------------------- stage 2a: streaming W transpose/pack (m13-shaped)
// Grid-stride; each wave reads 1 KB CONTIGUOUS of wr and wi, writes packed
// (Wr,Wi) u32 into Wp[k][d][e] (k stride 256K u32). No LDS, no barriers.
__global__ __launch_bounds__(256, 8) void k_wpack(
    const float* __restrict__ wr_, const float* __restrict__ wi_,
    unsigned* __restrict__ Wp) {
  const float4* r4 = (const float4*)wr_;
  const float4* i4 = (const float4*)wi_;
  int f0 = blockIdx.x * 256 + threadIdx.x;
#pragma unroll 2
  for (int it = 0; it < 8; ++it) {
    int f = f0 + it * 524288;               // 0..4194303 float4 units
    float4 r = r4[f];
    float4 i = i4[f];
    int d = f >> 13;                        // f = (d*512+e)*16 + k4
    int e = (f >> 4) & 511;
    int k4 = f & 15;
    unsigned* o = Wp + (size_t)(k4 * 4) * 262144 + d * 512 + e;
    o[0]      = packbf(r.x, i.x);
    o[262144] = packbf(r.y, i.y);
    o[524288] = packbf(r.z, i.z);
    o[786432] = packbf(r.w, i.w);
  }
}

// ------------------------- stage 2b: mode-mix from pre-packed Wp (k_dft-shaped)
// grid (64 k, 8 et), 256 thr = 4 waves; wave w -> e-subtile et*64 + w*16.
// No LDS, no barriers: A-frags read directly from Wp[k][d][e] (dword, dense),
// B-frags from Qbf + sign/rot. acc over all 512 d -> write bf16 P directly.
__global__ __launch_bounds__(256, 4) void k_mix2(
    const unsigned* __restrict__ Wp, const unsigned* __restrict__ Qbf,
    unsigned short* __restrict__ P) {
  int tid = threadIdx.x;
  int k = blockIdx.x;
  int et = blockIdx.y;
  int w = tid >> 6, lane = tid & 63;
  int er = lane & 15, kg = lane >> 4;
  int part = er >> 3, b = er & 7;
  int e0 = et * 64 + w * 16;

  const unsigned* wp = Wp + (size_t)k * 262144 + e0 + er;   // + d*512
  const unsigned* qb = Qbf + ((size_t)k * 8 + b) * 512 + kg * 4;

  f4 acc = {0.f, 0.f, 0.f, 0.f};
#pragma unroll 4
  for (int s = 0; s < 32; ++s) {
    int d = s * 16 + kg * 4;                // dpairs kg*4..+3 of this step
    union { u32x4 u; bh8 h; } av, bv;
    av.u.x = wp[(size_t)(d + 0) * 512];
    av.u.y = wp[(size_t)(d + 1) * 512];
    av.u.z = wp[(size_t)(d + 2) * 512];
    av.u.w = wp[(size_t)(d + 3) * 512];
    u32x4 q = *(const u32x4*)(qb + s * 16);
    if (part == 0) {
      bv.u.x = q.x ^ 0x80000000u; bv.u.y = q.y ^ 0x80000000u;
      bv.u.z = q.z ^ 0x80000000u; bv.u.w = q.w ^ 0x80000000u;
    } else {
      bv.u.x = (q.x >> 16) | (q.x << 16); bv.u.y = (q.y >> 16) | (q.y << 16);
      bv.u.z = (q.z >> 16) | (q.z << 16); bv.u.w = (q.w >> 16) | (q.w << 16);
    }
    acc = __builtin_amdgcn_mfma_f32_16x16x32_bf16(av.h, bv.h, acc, 0, 0, 0);
  }

  // D layout: col = er = (part,b); row = kg*4 + j = e offset
#pragma unroll
  for (int j = 0; j < 4; ++j) {
    int e = e0 + kg * 4 + j;
    P[((size_t)b * 512 + e) * 128 + part * 64 + k] = f2bf(acc[j]);
  }
}

// ------------------------- stage 3: y[b] = G(4096x128) * P[b](512x128)^T via MFMA
#define LST 72
__global__ __launch_bounds__(256, 2) void k_inv_mfma(
    const short* __restrict__ G, const short* __restrict__ P,
    float* __restrict__ y) {
  __shared__ short lds[2 * 128 * LST];
  short* As = lds;
  short* Bs = lds + 128 * LST;

  int tid = threadIdx.x;
  int lt = blockIdx.x, et = blockIdx.y, b = blockIdx.z;
  int l0 = lt * 128, e0 = et * 128;

  int wv = tid >> 6, lane = tid & 63;
  int wrow = wv >> 1, wcol = wv & 1;
  int lr = lane & 15, kg = lane >> 4;

  const short* Gb = G + (size_t)l0 * 128;
  const short* Pb = P + (size_t)b * D_ * 128 + (size_t)e0 * 128;

  f4 acc[4][4];
#pragma unroll
  for (int mi = 0; mi < 4; ++mi)
#pragma unroll
    for (int ni = 0; ni < 4; ++ni) {
      f4 z = {0.f, 0.f, 0.f, 0.f};
      acc[mi][ni] = z;
    }

#pragma unroll
  for (int kh = 0; kh < 2; ++kh) {
    if (kh) __syncthreads();
#pragma unroll
    for (int i = 0; i < 4; ++i) {
      int idx = i * 256 + tid;
      int row = idx >> 3, c = idx & 7;
      *(uint4*)(As + row * LST + c * 8) =
          *(const uint4*)(Gb + (size_t)row * 128 + kh * 64 + c * 8);
      *(uint4*)(Bs + row * LST + c * 8) =
          *(const uint4*)(Pb + (size_t)row * 128 + kh * 64 + c * 8);
    }
    __syncthreads();

#pragma unroll
    for (int ks = 0; ks < 2; ++ks) {
      bh8 a[4], bf[4];
#pragma unroll
      for (int i = 0; i < 4; ++i) {
        a[i]  = *(const bh8*)(As + (wrow * 64 + i * 16 + lr) * LST + ks * 32 + kg * 8);
        bf[i] = *(const bh8*)(Bs + (wcol * 64 + i * 16 + lr) * LST + ks * 32 + kg * 8);
      }
#pragma unroll
      for (int mi = 0; mi < 4; ++mi)
#pragma unroll
        for (int ni = 0; ni < 4; ++ni)
          acc[mi][ni] = __builtin_amdgcn_mfma_f32_16x16x32_bf16(
              a[mi], bf[ni], acc[mi][ni], 0, 0, 0);
    }
  }

#pragma unroll
  for (int mi = 0; mi < 4; ++mi) {
    int lg = l0 + wrow * 64 + mi * 16 + kg * 4;
#pragma unroll
    for (int ni = 0; ni < 4; ++ni) {
      int e = e0 + wcol * 64 + ni * 16 + lr;
#pragma unroll
      for (int j = 0; j < 4; ++j)
        y[((size_t)b * L_ + (lg + j)) * D_ + e] = acc[mi][ni][j];
    }
  }
}

// --------------------------------------------------------------------- launcher
extern "C" void kernel_launch(void* const* d_in, const int* in_sizes, int n_in,
                              void* d_out, int out_size, void* d_ws, size_t ws_size,
                              hipStream_t stream) {
  const float* q  = (const float*)d_in[0];
  const float* wr = (const float*)d_in[1];
  const float* wi = (const float*)d_in[2];
  float* out = (float*)d_out;
  char* ws = (char*)d_ws;

  // ws: Fbf 1MB | Gbf 1MB | Qbf 1MB | Pw 1MB = 4 MB (<=10MB proven)
  unsigned short* Fbf = (unsigned short*)ws;
  unsigned short* Gbf = (unsigned short*)(ws + (1u << 20));
  unsigned* Qbf       = (unsigned*)(ws + (2u << 20));
  unsigned short* Pw  = (unsigned short*)(ws + (3u << 20));

  // d_out scratch phases (stream-ordered):
  //   k_dft_mfma -> pQ (16.8 MB), consumed by k_red2;
  //   k_wpack    -> Wp (ALL 64 MB of d_out; pQ dead), consumed by k_mix2;
  //   k_inv_mfma overwrites all 64 MB.
  float* pQ    = out;
  unsigned* Wp = (unsigned*)out;

  hipLaunchKernelGGL(k_ftab, dim3((128 * L_) / 256), dim3(256), 0, stream, Fbf);
  hipLaunchKernelGGL(k_gtab, dim3((L_ * 128) / 256), dim3(256), 0, stream, Gbf);
  hipLaunchKernelGGL(k_dft_mfma, dim3(8, 8, 8), dim3(512), 0, stream,
                     q, Fbf, pQ);
  hipLaunchKernelGGL(k_red2, dim3(65536 / 256), dim3(256), 0, stream, pQ, Qbf);
  hipLaunchKernelGGL(k_wpack, dim3(2048), dim3(256), 0, stream, wr, wi, Wp);
  hipLaunchKernelGGL(k_mix2, dim3(64, 8), dim3(256), 0, stream, Wp, Qbf, Pw);
  hipLaunchKernelGGL(k_inv_mfma, dim3(L_ / 128, D_ / 128, B_), dim3(256), 0,
                     stream, (const short*)Gbf, (const short*)Pw, out);
}

// Round 20
// 97.893 us; speedup vs baseline: 1.4989x; 1.4989x over previous
//
#include <hip/hip_runtime.h>

#define B_ 8
#define L_ 4096
#define D_ 512
#define M_ 64

typedef __attribute__((ext_vector_type(8))) short bh8;
typedef __attribute__((ext_vector_type(4))) float f4;
typedef __attribute__((ext_vector_type(4))) unsigned u32x4;

__device__ inline unsigned short f2bf(float f) {
  unsigned u = __float_as_uint(f);
  return (unsigned short)((u + 0x7fffu + ((u >> 16) & 1u)) >> 16);
}
__device__ inline unsigned packbf(float lo, float hi) {
  return (unsigned)f2bf(lo) | ((unsigned)f2bf(hi) << 16);
}

#define TWOPI_OVER_L 0.00153398078788564122971808758949f  // 2*pi/4096

// ---------------- forward-DFT coefficient matrix (bf16), PLAIN row-major [r][l]
__global__ void k_ftab(unsigned short* __restrict__ F) {
  int t = blockIdx.x * 256 + threadIdx.x;  // 128*4096
  int r = t >> 12, l = t & 4095;
  int k = r & 63, part = r >> 6;
  int ph = (k * l) & (L_ - 1);
  float ang = (float)ph * TWOPI_OVER_L;
  float v = part ? -__sinf(ang) : __cosf(ang);
  F[t] = f2bf(v);
}

// ----------------------------------------- inverse-DFT coefficient matrix (bf16)
__global__ void k_gtab(unsigned short* __restrict__ G) {
  int t = blockIdx.x * 256 + threadIdx.x;  // L_*128
  int l = t >> 7, j = t & 127;
  int k = j & 63, part = j >> 6;
  int ph = (k * l) & (L_ - 1);
  float ang = (float)ph * TWOPI_OVER_L;
  float ck = (k == 0 ? 1.0f : 2.0f) / (float)L_;
  float v = part ? (-ck * __sinf(ang)) : (ck * __cosf(ang));
  G[t] = f2bf(v);
}

// ------------------------- stage 1: Qft = F(128x4096) * q[b](4096x512) via MFMA
__global__ __launch_bounds__(512, 4) void k_dft_mfma(
    const float* __restrict__ q, const unsigned short* __restrict__ F,
    float* __restrict__ pQ) {
  int tid = threadIdx.x;
  int dt = blockIdx.x, b = blockIdx.y, kc = blockIdx.z;
  int d0 = dt * 64;
  int lbase = kc * 512;

  int w = tid >> 6, lane = tid & 63;
  int mh = w & 3, nc = w >> 2;
  int lr = lane & 15, kg = lane >> 4;

  f4 acc[2][2];
#pragma unroll
  for (int i = 0; i < 2; ++i)
#pragma unroll
    for (int j = 0; j < 2; ++j) { f4 z = {0.f, 0.f, 0.f, 0.f}; acc[i][j] = z; }

  const unsigned short* A0 = F + (size_t)(mh * 32 + lr) * 4096 + lbase + kg * 8;
  const unsigned short* A1 = A0 + (size_t)16 * 4096;
  const float* q0 = q + ((size_t)b * L_ + lbase + kg * 8) * D_ + d0 + nc * 32 + lr;

#pragma unroll 2
  for (int s = 0; s < 16; ++s) {
    const float* qs = q0 + (size_t)s * 32 * D_;
    float v0[8], v1[8];
#pragma unroll
    for (int j = 0; j < 8; ++j) {
      v0[j] = qs[(size_t)j * D_];
      v1[j] = qs[(size_t)j * D_ + 16];
    }
    union { u32x4 u; bh8 h; } bf0, bf1;
    bf0.u.x = packbf(v0[0], v0[1]); bf0.u.y = packbf(v0[2], v0[3]);
    bf0.u.z = packbf(v0[4], v0[5]); bf0.u.w = packbf(v0[6], v0[7]);
    bf1.u.x = packbf(v1[0], v1[1]); bf1.u.y = packbf(v1[2], v1[3]);
    bf1.u.z = packbf(v1[4], v1[5]); bf1.u.w = packbf(v1[6], v1[7]);
    bh8 af0 = *(const bh8*)(A0 + s * 32);
    bh8 af1 = *(const bh8*)(A1 + s * 32);
    acc[0][0] = __builtin_amdgcn_mfma_f32_16x16x32_bf16(af0, bf0.h, acc[0][0], 0, 0, 0);
    acc[0][1] = __builtin_amdgcn_mfma_f32_16x16x32_bf16(af0, bf1.h, acc[0][1], 0, 0, 0);
    acc[1][0] = __builtin_amdgcn_mfma_f32_16x16x32_bf16(af1, bf0.h, acc[1][0], 0, 0, 0);
    acc[1][1] = __builtin_amdgcn_mfma_f32_16x16x32_bf16(af1, bf1.h, acc[1][1], 0, 0, 0);
  }

#pragma unroll
  for (int mi = 0; mi < 2; ++mi) {
    int r = mh * 32 + mi * 16 + kg * 4;
#pragma unroll
    for (int ni = 0; ni < 2; ++ni) {
      int d = d0 + nc * 32 + ni * 16 + lr;
#pragma unroll
      for (int j = 0; j < 4; ++j)
        pQ[(((size_t)kc * 128 + (r + j)) * 8 + b) * 512 + d] = acc[mi][ni][j];
    }
  }
}

// -------------- reduce kc chunks + pack bf16 Qbf[k][b][d]: word = (Qr, Qi)
__global__ __launch_bounds__(256) void k_red2(const float* __restrict__ pQ,
                                              unsigned* __restrict__ Qbf) {
  int g = blockIdx.x * 256 + threadIdx.x;  // 64*8*128 = 65536
  int dq = g & 127;
  int b = (g >> 7) & 7;
  int k = g >> 10;
  f4 sr = {0.f, 0.f, 0.f, 0.f}, si = {0.f, 0.f, 0.f, 0.f};
#pragma unroll
  for (int kc = 0; kc < 8; ++kc) {
    size_t base = (((size_t)kc * 128 + k) * 8 + b) * 512 + dq * 4;
    sr += *(const f4*)(pQ + base);
    si += *(const f4*)(pQ + base + (size_t)64 * 8 * 512);
  }
  u32x4 o;
  o.x = packbf(sr[0], si[0]); o.y = packbf(sr[1], si[1]);
  o.z = packbf(sr[2], si[2]); o.w = packbf(sr[3], si[3]);
  *(u32x4*)(Qbf + ((size_t)k * 8 + b) * 512 + dq * 4) = o;
}

// ------------------------- stage 2 v7 (best measured): asm-load register
// staging, counted vmcnt. grid (32 et, 2 kh, 8 dc) = 512 blocks, 2/CU.
__global__ __launch_bounds__(512, 4) void k_mix_mfma(
    const float* __restrict__ wr_, const float* __restrict__ wi_,
    const unsigned* __restrict__ Qbf, float* __restrict__ pOut) {
  __shared__ unsigned Wt[2][8192];  // 2 x 32 KB: [kl32][e16][dp16] packed (Wr,Wi)

  int tid = threadIdx.x;
  int et = blockIdx.x, kh = blockIdx.y, dc = blockIdx.z;
  int e0 = et * 16, D0 = dc * 64;
  int w = tid >> 6, lane = tid & 63;
  int er = lane & 15, kg = lane >> 4;
  int part = er >> 3, b = er & 7;

  int e8 = lane >> 3, k4g = lane & 7;
  int koff = kh * 32 + k4g * 4;
  int swl = (k4g & 3) << 2;
  int dloc0 = w * 2;

  const unsigned* qlane =
      Qbf + ((size_t)(kh * 32 + w * 4) * 8 + b) * 512 + D0 + kg * 4;

  f4 acc[4];
#pragma unroll
  for (int t = 0; t < 4; ++t) { f4 z = {0.f, 0.f, 0.f, 0.f}; acc[t] = z; }

  f4 LR0, LR1, LR2, LR3, LI0, LI1, LI2, LI3;      // W staging regs (1 round)
  u32x4 QA0, QA1, QA2, QA3, QB0, QB1, QB2, QB3;   // Q regs (2 rounds)

#define GLD(dst, p) \
  asm volatile("global_load_dwordx4 %0, %1, off" : "=v"(dst) : "v"(p))
#define SB() __builtin_amdgcn_sched_barrier(0)
#define VMW(n) do { asm volatile("s_waitcnt vmcnt(" #n ")" ::: "memory"); SB(); } while (0)
#define LKM0() do { asm volatile("s_waitcnt lgkmcnt(0)" ::: "memory"); SB(); } while (0)
#define BAR() do { __builtin_amdgcn_s_barrier(); SB(); } while (0)

#define LOADL(r) do {                                                        \
    size_t d_ = (size_t)(D0 + 16 * (r) + dloc0);                             \
    const float* p00 = wr_ + (d_ * 512 + e0 + e8) * 64 + koff;               \
    const float* p01 = wr_ + (d_ * 512 + e0 + 8 + e8) * 64 + koff;           \
    const float* p10 = wr_ + ((d_ + 1) * 512 + e0 + e8) * 64 + koff;         \
    const float* p11 = wr_ + ((d_ + 1) * 512 + e0 + 8 + e8) * 64 + koff;     \
    const float* q00 = wi_ + (d_ * 512 + e0 + e8) * 64 + koff;               \
    const float* q01 = wi_ + (d_ * 512 + e0 + 8 + e8) * 64 + koff;           \
    const float* q10 = wi_ + ((d_ + 1) * 512 + e0 + e8) * 64 + koff;         \
    const float* q11 = wi_ + ((d_ + 1) * 512 + e0 + 8 + e8) * 64 + koff;     \
    GLD(LR0, p00); GLD(LR1, p01); GLD(LR2, p10); GLD(LR3, p11);              \
    GLD(LI0, q00); GLD(LI1, q01); GLD(LI2, q10); GLD(LI3, q11);              \
  } while (0)

#define LOADQ(q0_, q1_, q2_, q3_, r) do {                                    \
    GLD(q0_, (const float*)(qlane + (r) * 16));                              \
    GLD(q1_, (const float*)(qlane + 4096 + (r) * 16));                       \
    GLD(q2_, (const float*)(qlane + 8192 + (r) * 16));                       \
    GLD(q3_, (const float*)(qlane + 12288 + (r) * 16));                      \
  } while (0)

#define PACK1(wb, vr, vi, dl, el) do {                                       \
    int dp_ = (dl) ^ swl;                                                    \
    unsigned* o_ = &Wt[wb][(k4g * 4) * 256 + (el) * 16 + dp_];               \
    o_[0]   = packbf(vr[0], vi[0]);                                          \
    o_[256] = packbf(vr[1], vi[1]);                                          \
    o_[512] = packbf(vr[2], vi[2]);                                          \
    o_[768] = packbf(vr[3], vi[3]);                                          \
  } while (0)

#define PACKL(wb) do {                                                      \
    PACK1(wb, LR0, LI0, dloc0, e8);                                         \
    PACK1(wb, LR1, LI1, dloc0, 8 + e8);                                     \
    PACK1(wb, LR2, LI2, dloc0 + 1, e8);                                     \
    PACK1(wb, LR3, LI3, dloc0 + 1, 8 + e8);                                 \
  } while (0)

#define COMPW(wb, q0_, q1_, q2_, q3_) do {                                  \
    u32x4 qarr0 = q0_, qarr1 = q1_, qarr2 = q2_, qarr3 = q3_;               \
    _Pragma("unroll") for (int t = 0; t < 4; ++t) {                         \
      int kl_ = w * 4 + t;                                                  \
      int sw_ = ((kl_ >> 2) & 3) << 2;                                      \
      union { u32x4 u; bh8 h; } av, bv;                                     \
      av.u = *(const u32x4*)&Wt[wb][kl_ * 256 + er * 16 + ((kg * 4) ^ sw_)]; \
      u32x4 q = (t == 0) ? qarr0 : (t == 1) ? qarr1 : (t == 2) ? qarr2 : qarr3; \
      if (part == 0) {                                                      \
        bv.u.x = q.x ^ 0x80000000u; bv.u.y = q.y ^ 0x80000000u;             \
        bv.u.z = q.z ^ 0x80000000u; bv.u.w = q.w ^ 0x80000000u;             \
      } else {                                                              \
        bv.u.x = (q.x >> 16) | (q.x << 16); bv.u.y = (q.y >> 16) | (q.y << 16); \
        bv.u.z = (q.z >> 16) | (q.z << 16); bv.u.w = (q.w >> 16) | (q.w << 16); \
      }                                                                     \
      acc[t] = __builtin_amdgcn_mfma_f32_16x16x32_bf16(av.h, bv.h, acc[t], 0, 0, 0); \
    }                                                                       \
  } while (0)

  // ---- prologue: L0 -> Wt[0]
  LOADL(0);
  VMW(0);
  PACKL(0);
  LOADL(1);                       // out: L1(8)
  LOADQ(QA0, QA1, QA2, QA3, 0);   // out: L1(8), Q0(4) = 12

  // ---- round 0
  VMW(4);                         // L1 landed (leaves Q0)
  PACKL(1);
  LKM0(); BAR();
  LOADL(2);
  LOADQ(QB0, QB1, QB2, QB3, 1);   // out: Q0(4), L2(8), Q1(4) = 16
  VMW(12);                        // Q0 landed
  COMPW(0, QA0, QA1, QA2, QA3);
  LKM0(); BAR();

  // ---- round 1
  VMW(4);                         // L2 landed (leaves Q1)
  PACKL(0);
  LKM0(); BAR();
  LOADL(3);
  LOADQ(QA0, QA1, QA2, QA3, 2);   // out: Q1(4), L3(8), Q2(4) = 16
  VMW(12);                        // Q1 landed
  COMPW(1, QB0, QB1, QB2, QB3);
  LKM0(); BAR();

  // ---- round 2
  VMW(4);                         // L3 landed (leaves Q2)
  PACKL(1);
  LKM0(); BAR();
  LOADQ(QB0, QB1, QB2, QB3, 3);   // out: Q2(4), Q3(4) = 8
  VMW(4);                         // Q2 landed
  COMPW(0, QA0, QA1, QA2, QA3);
  LKM0(); BAR();

  // ---- round 3 (tail)
  VMW(0);                         // Q3 landed
  COMPW(1, QB0, QB1, QB2, QB3);

#undef GLD
#undef SB
#undef VMW
#undef LKM0
#undef BAR
#undef LOADL
#undef LOADQ
#undef PACK1
#undef PACKL
#undef COMPW

  // epilogue: pOut[dc][k*2+part][b][e512]
#pragma unroll
  for (int t = 0; t < 4; ++t) {
    int kglob = kh * 32 + w * 4 + t;
    size_t off = (size_t)dc * 524288 +
                 (((size_t)kglob * 2 + part) * 8 + b) * 512 + e0 + kg * 4;
    *(f4*)(pOut + off) = acc[t];
  }
}

// ------------- reduce pOut over 8 dc + transpose to bf16 P[b][e][part*64+k]
__global__ __launch_bounds__(512) void k_psum2(const float* __restrict__ pOut,
                                               unsigned* __restrict__ Pw) {
  __shared__ float sP[128 * 33];
  int tid = threadIdx.x;
  int e0 = blockIdx.x * 32, b = blockIdx.y;
  {
    int e = tid & 31, g = tid >> 5;  // 16 groups of 8 cols
#pragma unroll
    for (int ii = 0; ii < 8; ++ii) {
      int col = g * 8 + ii;                          // col = part*64 + k
      int rkp = ((col & 63) << 1) | (col >> 6);      // pOut row = k*2 + part
      float s = 0.f;
#pragma unroll
      for (int c = 0; c < 8; ++c)
        s += pOut[(size_t)c * 524288 + (size_t)rkp * 4096 + b * 512 + e0 + e];
      sP[col * 33 + e] = s;
    }
  }
  __syncthreads();
  {
    int e = tid >> 4, c = tid & 15;  // e 0..31, 8 cols each
    size_t wbase = (((size_t)b * 512 + e0 + e) * 128 + c * 8) >> 1;
#pragma unroll
    for (int ii = 0; ii < 4; ++ii) {
      int col = c * 8 + ii * 2;
      Pw[wbase + ii] = packbf(sP[col * 33 + e], sP[(col + 1) * 33 + e]);
    }
  }
}

// ------------------------- stage 3: y[b] = G(4096x128) * P[b](512x128)^T via MFMA
#define LST 72
__global__ __launch_bounds__(256, 2) void k_inv_mfma(
    const short* __restrict__ G, const short* __restrict__ P,
    float* __restrict__ y) {
  __shared__ short lds[2 * 128 * LST];
  short* As = lds;
  short* Bs = lds + 128 * LST;

  int tid = threadIdx.x;
  int lt = blockIdx.x, et = blockIdx.y, b = blockIdx.z;
  int l0 = lt * 128, e0 = et * 128;

  int wv = tid >> 6, lane = tid & 63;
  int wrow = wv >> 1, wcol = wv & 1;
  int lr = lane & 15, kg = lane >> 4;

  const short* Gb = G + (size_t)l0 * 128;
  const short* Pb = P + (size_t)b * D_ * 128 + (size_t)e0 * 128;

  f4 acc[4][4];
#pragma unroll
  for (int mi = 0; mi < 4; ++mi)
#pragma unroll
    for (int ni = 0; ni < 4; ++ni) {
      f4 z = {0.f, 0.f, 0.f, 0.f};
      acc[mi][ni] = z;
    }

#pragma unroll
  for (int kh = 0; kh < 2; ++kh) {
    if (kh) __syncthreads();
#pragma unroll
    for (int i = 0; i < 4; ++i) {
      int idx = i * 256 + tid;
      int row = idx >> 3, c = idx & 7;
      *(uint4*)(As + row * LST + c * 8) =
          *(const uint4*)(Gb + (size_t)row * 128 + kh * 64 + c * 8);
      *(uint4*)(Bs + row * LST + c * 8) =
          *(const uint4*)(Pb + (size_t)row * 128 + kh * 64 + c * 8);
    }
    __syncthreads();

#pragma unroll
    for (int ks = 0; ks < 2; ++ks) {
      bh8 a[4], bf[4];
#pragma unroll
      for (int i = 0; i < 4; ++i) {
        a[i]  = *(const bh8*)(As + (wrow * 64 + i * 16 + lr) * LST + ks * 32 + kg * 8);
        bf[i] = *(const bh8*)(Bs + (wcol * 64 + i * 16 + lr) * LST + ks * 32 + kg * 8);
      }
#pragma unroll
      for (int mi = 0; mi < 4; ++mi)
#pragma unroll
        for (int ni = 0; ni < 4; ++ni)
          acc[mi][ni] = __builtin_amdgcn_mfma_f32_16x16x32_bf16(
              a[mi], bf[ni], acc[mi][ni], 0, 0, 0);
    }
  }

#pragma unroll
  for (int mi = 0; mi < 4; ++mi) {
    int lg = l0 + wrow * 64 + mi * 16 + kg * 4;
#pragma unroll
    for (int ni = 0; ni < 4; ++ni) {
      int e = e0 + wcol * 64 + ni * 16 + lr;
#pragma unroll
      for (int j = 0; j < 4; ++j)
        y[((size_t)b * L_ + (lg + j)) * D_ + e] = acc[mi][ni][j];
    }
  }
}

// --------------------------------------------------------------------- launcher
extern "C" void kernel_launch(void* const* d_in, const int* in_sizes, int n_in,
                              void* d_out, int out_size, void* d_ws, size_t ws_size,
                              hipStream_t stream) {
  const float* q  = (const float*)d_in[0];
  const float* wr = (const float*)d_in[1];
  const float* wi = (const float*)d_in[2];
  float* out = (float*)d_out;
  char* ws = (char*)d_ws;

  // ws: Fbf 1MB | Gbf 1MB | Qbf 1MB | Pw 1MB = 4 MB (<=10MB proven)
  unsigned short* Fbf = (unsigned short*)ws;
  unsigned short* Gbf = (unsigned short*)(ws + (1u << 20));
  unsigned* Qbf       = (unsigned*)(ws + (2u << 20));
  unsigned* Pw        = (unsigned*)(ws + (3u << 20));

  // d_out scratch phases (stream-ordered):
  //   k_dft_mfma -> pQ (16.8 MB), consumed by k_red2;
  //   k_mix_mfma -> pOut (16.8 MB), consumed by k_psum2;
  //   k_inv_mfma overwrites all 64 MB.
  float* pQ   = out;
  float* pOut = out;

  hipLaunchKernelGGL(k_ftab, dim3((128 * L_) / 256), dim3(256), 0, stream, Fbf);
  hipLaunchKernelGGL(k_gtab, dim3((L_ * 128) / 256), dim3(256), 0, stream, Gbf);
  hipLaunchKernelGGL(k_dft_mfma, dim3(8, 8, 8), dim3(512), 0, stream,
                     q, Fbf, pQ);
  hipLaunchKernelGGL(k_red2, dim3(65536 / 256), dim3(256), 0, stream, pQ, Qbf);
  hipLaunchKernelGGL(k_mix_mfma, dim3(32, 2, 8), dim3(512), 0, stream,
                     wr, wi, Qbf, pOut);
  hipLaunchKernelGGL(k_psum2, dim3(16, 8), dim3(512), 0, stream, pOut, Pw);
  hipLaunchKernelGGL(k_inv_mfma, dim3(L_ / 128, D_ / 128, B_), dim3(256), 0,
                     stream, (const short*)Gbf, (const short*)Pw, out);
}